// Round 1
// baseline (2303.974 us; speedup 1.0000x reference)
//
#include <hip/hip_runtime.h>
#include <math.h>

#define N_TOK  131072
#define DIM    1024
#define HIDN   256
#define ATTN   128
#define NSEG   64
#define SEGLEN 2048
#define NCLS   2
#define EPSLN  1e-5f
#define SROWS  32

__device__ __forceinline__ float gelu_exact(float x) {
    return 0.5f * x * (1.0f + erff(x * 0.70710678118654752f));
}

// C[M x 256] = A[M x K] @ B[K x 256] + bias ; BM=BN=64, BK=16, 256 thr, 4x4 microtile
template <int K>
__global__ __launch_bounds__(256) void sgemm_bias(const float* __restrict__ A,
                                                  const float* __restrict__ Bw,
                                                  const float* __restrict__ bias,
                                                  float* __restrict__ C) {
    __shared__ float As[16][68];   // padded: 16B-aligned rows, spread banks
    __shared__ float Bs[16][64];
    const int tid  = threadIdx.x;
    const int row0 = blockIdx.y * 64;
    const int col0 = blockIdx.x * 64;
    const int tx = tid & 15, ty = tid >> 4;
    const int ar = tid >> 2, ac4 = tid & 3;    // A-tile load coords
    const int br = tid >> 4, bc4 = tid & 15;   // B-tile load coords

    float acc[4][4] = {};

    for (int k0 = 0; k0 < K; k0 += 16) {
        float4 av = *(const float4*)&A[(size_t)(row0 + ar) * K + k0 + ac4 * 4];
        float4 bv = *(const float4*)&Bw[(size_t)(k0 + br) * 256 + col0 + bc4 * 4];
        __syncthreads();   // previous tile fully consumed
        As[ac4 * 4 + 0][ar] = av.x;
        As[ac4 * 4 + 1][ar] = av.y;
        As[ac4 * 4 + 2][ar] = av.z;
        As[ac4 * 4 + 3][ar] = av.w;
        *(float4*)&Bs[br][bc4 * 4] = bv;
        __syncthreads();
#pragma unroll
        for (int kk = 0; kk < 16; kk++) {
            float4 a = *(const float4*)&As[kk][ty * 4];
            float4 b = *(const float4*)&Bs[kk][tx * 4];
            acc[0][0] += a.x * b.x; acc[0][1] += a.x * b.y; acc[0][2] += a.x * b.z; acc[0][3] += a.x * b.w;
            acc[1][0] += a.y * b.x; acc[1][1] += a.y * b.y; acc[1][2] += a.y * b.z; acc[1][3] += a.y * b.w;
            acc[2][0] += a.z * b.x; acc[2][1] += a.z * b.y; acc[2][2] += a.z * b.z; acc[2][3] += a.z * b.w;
            acc[3][0] += a.w * b.x; acc[3][1] += a.w * b.y; acc[3][2] += a.w * b.z; acc[3][3] += a.w * b.w;
        }
    }

    float4 bias4 = *(const float4*)&bias[col0 + tx * 4];
#pragma unroll
    for (int i = 0; i < 4; i++) {
        float4 o;
        o.x = acc[i][0] + bias4.x;
        o.y = acc[i][1] + bias4.y;
        o.z = acc[i][2] + bias4.z;
        o.w = acc[i][3] + bias4.w;
        *(float4*)&C[(size_t)(row0 + ty * 4 + i) * 256 + col0 + tx * 4] = o;
    }
}

// In-place LayerNorm + exact GELU over rows of 256. One wave per row, 4 rows/block.
__global__ __launch_bounds__(256) void ln_gelu_inplace(float* __restrict__ T,
                                                       const float* __restrict__ g,
                                                       const float* __restrict__ be) {
    const int wave = threadIdx.x >> 6;
    const int lane = threadIdx.x & 63;
    const int row  = blockIdx.x * 4 + wave;
    float4 v = *(float4*)&T[(size_t)row * HIDN + lane * 4];
    float s  = v.x + v.y + v.z + v.w;
    float sq = v.x * v.x + v.y * v.y + v.z * v.z + v.w * v.w;
#pragma unroll
    for (int o = 32; o > 0; o >>= 1) {
        s  += __shfl_down(s, o);
        sq += __shfl_down(sq, o);
    }
    s  = __shfl(s, 0);
    sq = __shfl(sq, 0);
    const float mu  = s * (1.0f / HIDN);
    const float var = sq * (1.0f / HIDN) - mu * mu;
    const float r   = rsqrtf(var + EPSLN);
    float4 gg = *(const float4*)&g[lane * 4];
    float4 bb = *(const float4*)&be[lane * 4];
    v.x = gelu_exact((v.x - mu) * r * gg.x + bb.x);
    v.y = gelu_exact((v.y - mu) * r * gg.y + bb.y);
    v.z = gelu_exact((v.z - mu) * r * gg.z + bb.z);
    v.w = gelu_exact((v.w - mu) * r * gg.w + bb.w);
    *(float4*)&T[(size_t)row * HIDN + lane * 4] = v;
}

// a[i] = sum_j tanh(v_j)*sigmoid(u_j)*Ww_j + bw  where v = h@Wv+bv, u = h@Wu+bu
// 128 threads (j = tid), SROWS rows per block staged in LDS.
__global__ __launch_bounds__(128) void scores_kernel(const float* __restrict__ H,
                                                     const float* __restrict__ Wv,
                                                     const float* __restrict__ bv,
                                                     const float* __restrict__ Wu,
                                                     const float* __restrict__ bu,
                                                     const float* __restrict__ Ww,
                                                     const float* __restrict__ bw,
                                                     float* __restrict__ Aout) {
    __shared__ float hs[SROWS][HIDN];   // 32 KB
    __shared__ float part[2][SROWS];
    const int tid  = threadIdx.x;       // j in [0,128)
    const int row0 = blockIdx.x * SROWS;

    for (int i = tid; i < SROWS * HIDN / 4; i += 128)
        ((float4*)&hs[0][0])[i] = ((const float4*)&H[(size_t)row0 * HIDN])[i];
    __syncthreads();

    float av[SROWS], au[SROWS];
#pragma unroll
    for (int r = 0; r < SROWS; r++) { av[r] = 0.0f; au[r] = 0.0f; }

    for (int k0 = 0; k0 < HIDN; k0 += 4) {
        float wv0 = Wv[(k0 + 0) * ATTN + tid], wv1 = Wv[(k0 + 1) * ATTN + tid];
        float wv2 = Wv[(k0 + 2) * ATTN + tid], wv3 = Wv[(k0 + 3) * ATTN + tid];
        float wu0 = Wu[(k0 + 0) * ATTN + tid], wu1 = Wu[(k0 + 1) * ATTN + tid];
        float wu2 = Wu[(k0 + 2) * ATTN + tid], wu3 = Wu[(k0 + 3) * ATTN + tid];
#pragma unroll
        for (int r = 0; r < SROWS; r++) {
            float4 h4 = *(const float4*)&hs[r][k0];
            av[r] += h4.x * wv0 + h4.y * wv1 + h4.z * wv2 + h4.w * wv3;
            au[r] += h4.x * wu0 + h4.y * wu1 + h4.z * wu2 + h4.w * wu3;
        }
    }

    const float wwj = Ww[tid];
    const float bvj = bv[tid];
    const float buj = bu[tid];
    const float bw0 = bw[0];
    const int lane = tid & 63, wid = tid >> 6;
#pragma unroll
    for (int r = 0; r < SROWS; r++) {
        float t   = tanhf(av[r] + bvj);
        float sg  = 1.0f / (1.0f + expf(-(au[r] + buj)));
        float val = t * sg * wwj;
#pragma unroll
        for (int o = 32; o > 0; o >>= 1) val += __shfl_down(val, o);
        if (lane == 0) part[wid][r] = val;
    }
    __syncthreads();
    if (tid < SROWS) Aout[row0 + tid] = part[0][tid] + part[1][tid] + bw0;
}

// One block per segment: softmax over 2048 scores, then z[c] = sum_i attn_i * h[i][c]
__global__ __launch_bounds__(256) void segment_pool(const float* __restrict__ Ain,
                                                    const float* __restrict__ H,
                                                    float* __restrict__ Z) {
    __shared__ float e[SEGLEN];   // 8 KB
    __shared__ float red[256];
    const int seg = blockIdx.x;
    const int tid = threadIdx.x;
    const float* a = Ain + (size_t)seg * SEGLEN;

    float m = -1e30f;
    for (int i = tid; i < SEGLEN; i += 256) m = fmaxf(m, a[i]);
    red[tid] = m; __syncthreads();
    for (int s = 128; s > 0; s >>= 1) {
        if (tid < s) red[tid] = fmaxf(red[tid], red[tid + s]);
        __syncthreads();
    }
    m = red[0]; __syncthreads();

    float sum = 0.0f;
    for (int i = tid; i < SEGLEN; i += 256) {
        float ev = expf(a[i] - m);
        e[i] = ev;
        sum += ev;
    }
    red[tid] = sum; __syncthreads();
    for (int s = 128; s > 0; s >>= 1) {
        if (tid < s) red[tid] += red[tid + s];
        __syncthreads();
    }
    const float inv = 1.0f / red[0];

    const float* h = H + (size_t)seg * SEGLEN * HIDN;
    float acc = 0.0f;
    for (int i = 0; i < SEGLEN; i++)
        acc += e[i] * h[(size_t)i * HIDN + tid];   // coalesced across tid
    Z[seg * HIDN + tid] = acc * inv;
}

// logits = gelu(z @ Wc1 + bc1) @ Wc2 + bc2 ; one block (128 thr) per segment
__global__ __launch_bounds__(128) void head_kernel(const float* __restrict__ Z,
                                                   const float* __restrict__ Wc1,
                                                   const float* __restrict__ bc1,
                                                   const float* __restrict__ Wc2,
                                                   const float* __restrict__ bc2,
                                                   float* __restrict__ Out) {
    __shared__ float zs[HIDN];
    __shared__ float hs[HIDN / 2];
    __shared__ float red[2];
    const int seg = blockIdx.x;
    const int tid = threadIdx.x;   // 128

    for (int i = tid; i < HIDN; i += 128) zs[i] = Z[seg * HIDN + i];
    __syncthreads();

    float acc = bc1[tid];
    for (int k = 0; k < HIDN; k++) acc += zs[k] * Wc1[k * (HIDN / 2) + tid];
    hs[tid] = gelu_exact(acc);
    __syncthreads();

    for (int c = 0; c < NCLS; c++) {
        float v = hs[tid] * Wc2[tid * NCLS + c];
#pragma unroll
        for (int o = 32; o > 0; o >>= 1) v += __shfl_down(v, o);
        if ((tid & 63) == 0) red[tid >> 6] = v;
        __syncthreads();
        if (tid == 0) Out[seg * NCLS + c] = red[0] + red[1] + bc2[c];
        __syncthreads();
    }
}

extern "C" void kernel_launch(void* const* d_in, const int* in_sizes, int n_in,
                              void* d_out, int out_size, void* d_ws, size_t ws_size,
                              hipStream_t stream) {
    const float* x   = (const float*)d_in[0];
    // d_in[1] = segment_ids (int32): segments are contiguous, size 2048 — computed arithmetically
    const float* W1  = (const float*)d_in[2];
    const float* b1  = (const float*)d_in[3];
    const float* g1  = (const float*)d_in[4];
    const float* be1 = (const float*)d_in[5];
    const float* W2  = (const float*)d_in[6];
    const float* b2  = (const float*)d_in[7];
    const float* g2  = (const float*)d_in[8];
    const float* be2 = (const float*)d_in[9];
    const float* Wv  = (const float*)d_in[10];
    const float* bv  = (const float*)d_in[11];
    const float* Wu  = (const float*)d_in[12];
    const float* bu  = (const float*)d_in[13];
    const float* Ww  = (const float*)d_in[14];
    const float* bw  = (const float*)d_in[15];
    const float* Wc1 = (const float*)d_in[16];
    const float* bc1 = (const float*)d_in[17];
    const float* Wc2 = (const float*)d_in[18];
    const float* bc2 = (const float*)d_in[19];
    float* out = (float*)d_out;

    float* bufA = (float*)d_ws;                       // N*HIDN  (h1)
    float* bufB = bufA + (size_t)N_TOK * HIDN;        // N*HIDN  (h2)
    float* bufC = bufB + (size_t)N_TOK * HIDN;        // N       (scores)
    float* bufZ = bufC + N_TOK;                       // NSEG*HIDN

    dim3 gg(HIDN / 64, N_TOK / 64);
    sgemm_bias<DIM><<<gg, 256, 0, stream>>>(x, W1, b1, bufA);
    ln_gelu_inplace<<<N_TOK / 4, 256, 0, stream>>>(bufA, g1, be1);
    sgemm_bias<HIDN><<<gg, 256, 0, stream>>>(bufA, W2, b2, bufB);
    ln_gelu_inplace<<<N_TOK / 4, 256, 0, stream>>>(bufB, g2, be2);
    scores_kernel<<<N_TOK / SROWS, 128, 0, stream>>>(bufB, Wv, bv, Wu, bu, Ww, bw, bufC);
    segment_pool<<<NSEG, 256, 0, stream>>>(bufC, bufB, bufZ);
    head_kernel<<<NSEG, 128, 0, stream>>>(bufZ, Wc1, bc1, Wc2, bc2, out);
}

// Round 2
// 1016.602 us; speedup vs baseline: 2.2663x; 2.2663x over previous
//
#include <hip/hip_runtime.h>
#include <math.h>

#define N_TOK  131072
#define DIM    1024
#define HIDN   256
#define ATTN   128
#define NSEG   64
#define SEGLEN 2048
#define NCLS   2
#define EPSLN  1e-5f

typedef __attribute__((ext_vector_type(8))) short  short8;
typedef __attribute__((ext_vector_type(4))) float  f32x4;

__device__ __forceinline__ unsigned short f2bf(float f) {
    unsigned int u = __float_as_uint(f);
    u += 0x7fffu + ((u >> 16) & 1u);
    return (unsigned short)(u >> 16);
}
__device__ __forceinline__ float bf2f(unsigned short h) {
    return __uint_as_float(((unsigned int)h) << 16);
}
__device__ __forceinline__ float gelu_exact(float x) {
    return 0.5f * x * (1.0f + erff(x * 0.70710678118654752f));
}

// out[C][R] (bf16) = transpose(in[R][C] fp32)
__global__ __launch_bounds__(256) void transpose_cvt(const float* __restrict__ in,
                                                     unsigned short* __restrict__ out,
                                                     int R, int C) {
    __shared__ float t[32][33];
    const int bx = blockIdx.x * 32;   // along C
    const int by = blockIdx.y * 32;   // along R
    const int x = threadIdx.x, y = threadIdx.y;  // 32 x 8
#pragma unroll
    for (int i = 0; i < 32; i += 8) {
        int r = by + y + i, c = bx + x;
        if (r < R && c < C) t[y + i][x] = in[(size_t)r * C + c];
    }
    __syncthreads();
#pragma unroll
    for (int i = 0; i < 32; i += 8) {
        int c = bx + y + i, r = by + x;
        if (c < C && r < R) out[(size_t)c * R + r] = f2bf(t[x][y + i]);
    }
}

__global__ void build_bvu(const float* __restrict__ bv, const float* __restrict__ bu,
                          float* __restrict__ bvu) {
    int t = threadIdx.x;
    bvu[t] = (t < 128) ? bv[t] : bu[t - 128];
}

// C[M x 256] = A[M x K] @ Wt^T + bias.  Wt is [256][K] bf16 (n-major, k contiguous).
// BM=64, BN=256 (full width), BK=32. 256 threads = 4 waves; wave w owns cols [64w,64w+64).
// MFMA 16x16x32 bf16: A[m=lane&15][k=(lane>>4)*8+j], B[k][n=lane&15], D[row=(lane>>4)*4+r][col=lane&15].
template <int K, bool AF32>
__global__ __launch_bounds__(256) void gemm_bf16(const void* __restrict__ Aptr,
                                                 const unsigned short* __restrict__ Wt,
                                                 const float* __restrict__ bias,
                                                 float* __restrict__ C) {
    __shared__ unsigned short As[64][40];    // stride 40 bf16 = 80 B (bank spread, 16B-aligned)
    __shared__ unsigned short Ws[256][40];
    const int tid  = threadIdx.x;
    const int wave = tid >> 6, lane = tid & 63;
    const int lr = lane & 15, lq = lane >> 4;
    const int srow = tid >> 2, skq = (tid & 3) * 8;
    const size_t row0 = (size_t)blockIdx.x * 64;

    f32x4 acc[4][4];
#pragma unroll
    for (int i = 0; i < 4; i++)
#pragma unroll
        for (int j = 0; j < 4; j++) acc[i][j] = (f32x4)0.0f;

    for (int k0 = 0; k0 < K; k0 += 32) {
        short8 aw;
        if constexpr (AF32) {
            const float* A = (const float*)Aptr;
            const float* p = &A[(row0 + srow) * K + k0 + skq];
            float4 v0 = *(const float4*)p;
            float4 v1 = *(const float4*)(p + 4);
            aw[0] = (short)f2bf(v0.x); aw[1] = (short)f2bf(v0.y);
            aw[2] = (short)f2bf(v0.z); aw[3] = (short)f2bf(v0.w);
            aw[4] = (short)f2bf(v1.x); aw[5] = (short)f2bf(v1.y);
            aw[6] = (short)f2bf(v1.z); aw[7] = (short)f2bf(v1.w);
        } else {
            const unsigned short* A = (const unsigned short*)Aptr;
            aw = *(const short8*)&A[(row0 + srow) * K + k0 + skq];
        }
        short8 ww[4];
#pragma unroll
        for (int c = 0; c < 4; c++)
            ww[c] = *(const short8*)&Wt[(size_t)(srow + 64 * c) * K + k0 + skq];

        __syncthreads();   // previous tile fully consumed
        *(short8*)&As[srow][skq] = aw;
#pragma unroll
        for (int c = 0; c < 4; c++)
            *(short8*)&Ws[srow + 64 * c][skq] = ww[c];
        __syncthreads();

        short8 a[4], b[4];
#pragma unroll
        for (int i = 0; i < 4; i++) a[i] = *(const short8*)&As[16 * i + lr][lq * 8];
#pragma unroll
        for (int j = 0; j < 4; j++) b[j] = *(const short8*)&Ws[64 * wave + 16 * j + lr][lq * 8];
#pragma unroll
        for (int i = 0; i < 4; i++)
#pragma unroll
            for (int j = 0; j < 4; j++)
                acc[i][j] = __builtin_amdgcn_mfma_f32_16x16x32_bf16(a[i], b[j], acc[i][j], 0, 0, 0);
    }

    float bj[4];
#pragma unroll
    for (int j = 0; j < 4; j++) bj[j] = bias[wave * 64 + 16 * j + lr];
#pragma unroll
    for (int i = 0; i < 4; i++)
#pragma unroll
        for (int j = 0; j < 4; j++)
#pragma unroll
            for (int r = 0; r < 4; r++)
                C[(row0 + 16 * i + lq * 4 + r) * 256 + wave * 64 + 16 * j + lr] = acc[i][j][r] + bj[j];
}

// LayerNorm + exact GELU over rows of 256; fp32 in, bf16 out. One wave/row, 4 rows/block.
__global__ __launch_bounds__(256) void ln_gelu_cvt(const float* __restrict__ Cin,
                                                   const float* __restrict__ g,
                                                   const float* __restrict__ be,
                                                   unsigned short* __restrict__ Hout) {
    const int row  = blockIdx.x * 4 + (threadIdx.x >> 6);
    const int lane = threadIdx.x & 63;
    float4 v = *(const float4*)&Cin[(size_t)row * HIDN + lane * 4];
    float s  = v.x + v.y + v.z + v.w;
    float sq = v.x * v.x + v.y * v.y + v.z * v.z + v.w * v.w;
#pragma unroll
    for (int o = 32; o > 0; o >>= 1) { s += __shfl_down(s, o); sq += __shfl_down(sq, o); }
    s  = __shfl(s, 0);
    sq = __shfl(sq, 0);
    const float mu  = s * (1.0f / HIDN);
    const float var = sq * (1.0f / HIDN) - mu * mu;
    const float r   = rsqrtf(var + EPSLN);
    float4 gg = *(const float4*)&g[lane * 4];
    float4 bb = *(const float4*)&be[lane * 4];
    ushort4 o4;
    o4.x = f2bf(gelu_exact((v.x - mu) * r * gg.x + bb.x));
    o4.y = f2bf(gelu_exact((v.y - mu) * r * gg.y + bb.y));
    o4.z = f2bf(gelu_exact((v.z - mu) * r * gg.z + bb.z));
    o4.w = f2bf(gelu_exact((v.w - mu) * r * gg.w + bb.w));
    *(ushort4*)&Hout[(size_t)row * HIDN + lane * 4] = o4;
}

// a[row] = sum_j tanh(VU[row][j]) * sigmoid(VU[row][128+j]) * Ww[j] + bw  (biases already in VU)
__global__ __launch_bounds__(256) void score_act(const float* __restrict__ VU,
                                                 const float* __restrict__ Ww,
                                                 const float* __restrict__ bw,
                                                 float* __restrict__ Aout) {
    const int row  = blockIdx.x * 4 + (threadIdx.x >> 6);
    const int lane = threadIdx.x & 63;
    const float* p = VU + (size_t)row * 256;
    float2 v = *(const float2*)&p[2 * lane];
    float2 u = *(const float2*)&p[128 + 2 * lane];
    float2 w = *(const float2*)&Ww[2 * lane];
    float val = tanhf(v.x) * (1.0f / (1.0f + expf(-u.x))) * w.x
              + tanhf(v.y) * (1.0f / (1.0f + expf(-u.y))) * w.y;
#pragma unroll
    for (int o = 32; o > 0; o >>= 1) val += __shfl_down(val, o);
    if (lane == 0) Aout[row] = val + bw[0];
}

// In-place softmax over each contiguous segment of 2048 scores.
__global__ __launch_bounds__(256) void seg_softmax(float* __restrict__ A) {
    __shared__ float red[256];
    const int seg = blockIdx.x, tid = threadIdx.x;
    float* a = A + (size_t)seg * SEGLEN;
    float m = -1e30f;
#pragma unroll
    for (int c = 0; c < 8; c++) m = fmaxf(m, a[tid + 256 * c]);
    red[tid] = m; __syncthreads();
    for (int s = 128; s > 0; s >>= 1) {
        if (tid < s) red[tid] = fmaxf(red[tid], red[tid + s]);
        __syncthreads();
    }
    m = red[0]; __syncthreads();
    float e[8]; float sum = 0.0f;
#pragma unroll
    for (int c = 0; c < 8; c++) { e[c] = expf(a[tid + 256 * c] - m); sum += e[c]; }
    red[tid] = sum; __syncthreads();
    for (int s = 128; s > 0; s >>= 1) {
        if (tid < s) red[tid] += red[tid + s];
        __syncthreads();
    }
    const float inv = 1.0f / red[0];
#pragma unroll
    for (int c = 0; c < 8; c++) a[tid + 256 * c] = e[c] * inv;
}

// Zp[b][col] = sum over 256 rows (b = seg*8+chunk) of attn[row]*h[row][col]
__global__ __launch_bounds__(256) void pool_partial(const float* __restrict__ Attn,
                                                    const unsigned short* __restrict__ H,
                                                    float* __restrict__ Zp) {
    __shared__ float aw[256];
    const int tid = threadIdx.x;
    const size_t rbase = (size_t)blockIdx.x * 256;
    aw[tid] = Attn[rbase + tid];
    __syncthreads();
    const unsigned short* h = H + rbase * 256 + tid;
    float acc = 0.0f;
    for (int r = 0; r < 256; r++) acc += aw[r] * bf2f(h[(size_t)r * 256]);
    Zp[rbase + tid] = acc;
}

// z = sum of 8 partials; logits = gelu(z @ Wc1 + bc1) @ Wc2 + bc2. One 256-thr block per segment.
__global__ __launch_bounds__(256) void head_kernel(const float* __restrict__ Zp,
                                                   const float* __restrict__ Wc1,
                                                   const float* __restrict__ bc1,
                                                   const float* __restrict__ Wc2,
                                                   const float* __restrict__ bc2,
                                                   float* __restrict__ Out) {
    __shared__ float zs[256];
    __shared__ float hs[128];
    __shared__ float red[4];
    const int seg = blockIdx.x, tid = threadIdx.x;
    float z = 0.0f;
#pragma unroll
    for (int c = 0; c < 8; c++) z += Zp[((size_t)seg * 8 + c) * 256 + tid];
    zs[tid] = z;
    __syncthreads();
    if (tid < 128) {
        float acc = bc1[tid];
        for (int k = 0; k < 256; k++) acc += zs[k] * Wc1[k * 128 + tid];
        hs[tid] = gelu_exact(acc);
    }
    __syncthreads();
    const int cls = tid >> 7, j = tid & 127;
    float val = hs[j] * Wc2[j * 2 + cls];
#pragma unroll
    for (int o = 32; o > 0; o >>= 1) val += __shfl_down(val, o);
    if ((tid & 63) == 0) red[tid >> 6] = val;
    __syncthreads();
    if (tid < 2) Out[seg * 2 + tid] = red[tid * 2] + red[tid * 2 + 1] + bc2[tid];
}

extern "C" void kernel_launch(void* const* d_in, const int* in_sizes, int n_in,
                              void* d_out, int out_size, void* d_ws, size_t ws_size,
                              hipStream_t stream) {
    const float* x   = (const float*)d_in[0];
    const float* W1  = (const float*)d_in[2];
    const float* b1  = (const float*)d_in[3];
    const float* g1  = (const float*)d_in[4];
    const float* be1 = (const float*)d_in[5];
    const float* W2  = (const float*)d_in[6];
    const float* b2  = (const float*)d_in[7];
    const float* g2  = (const float*)d_in[8];
    const float* be2 = (const float*)d_in[9];
    const float* Wv  = (const float*)d_in[10];
    const float* bv  = (const float*)d_in[11];
    const float* Wu  = (const float*)d_in[12];
    const float* bu  = (const float*)d_in[13];
    const float* Ww  = (const float*)d_in[14];
    const float* bw  = (const float*)d_in[15];
    const float* Wc1 = (const float*)d_in[16];
    const float* bc1 = (const float*)d_in[17];
    const float* Wc2 = (const float*)d_in[18];
    const float* bc2 = (const float*)d_in[19];
    float* out = (float*)d_out;

    char* p = (char*)d_ws;
    float*          bufA   = (float*)p;          p += (size_t)N_TOK * HIDN * 4;  // 134.2 MB (C1/C2/VU)
    unsigned short* h1b    = (unsigned short*)p; p += (size_t)N_TOK * HIDN * 2;  // 67 MB
    unsigned short* h2b    = (unsigned short*)p; p += (size_t)N_TOK * HIDN * 2;  // 67 MB
    float*          scores = (float*)p;          p += (size_t)N_TOK * 4;
    unsigned short* W1t    = (unsigned short*)p; p += (size_t)HIDN * DIM * 2;
    unsigned short* W2t    = (unsigned short*)p; p += (size_t)HIDN * HIDN * 2;
    unsigned short* Wvut   = (unsigned short*)p; p += (size_t)HIDN * HIDN * 2;
    float*          bvu    = (float*)p;          p += 256 * 4;
    float*          Zp     = (float*)p;          p += (size_t)NSEG * 8 * HIDN * 4;

    dim3 tb(32, 8);
    transpose_cvt<<<dim3(HIDN / 32, DIM / 32), tb, 0, stream>>>(W1, W1t, DIM, HIDN);
    transpose_cvt<<<dim3(HIDN / 32, HIDN / 32), tb, 0, stream>>>(W2, W2t, HIDN, HIDN);
    transpose_cvt<<<dim3(ATTN / 32, HIDN / 32), tb, 0, stream>>>(Wv, Wvut, HIDN, ATTN);
    transpose_cvt<<<dim3(ATTN / 32, HIDN / 32), tb, 0, stream>>>(Wu, Wvut + (size_t)ATTN * HIDN, HIDN, ATTN);
    build_bvu<<<1, 256, 0, stream>>>(bv, bu, bvu);

    gemm_bf16<DIM, true><<<N_TOK / 64, 256, 0, stream>>>(x, W1t, b1, bufA);
    ln_gelu_cvt<<<N_TOK / 4, 256, 0, stream>>>(bufA, g1, be1, h1b);
    gemm_bf16<HIDN, false><<<N_TOK / 64, 256, 0, stream>>>(h1b, W2t, b2, bufA);
    ln_gelu_cvt<<<N_TOK / 4, 256, 0, stream>>>(bufA, g2, be2, h2b);
    gemm_bf16<HIDN, false><<<N_TOK / 64, 256, 0, stream>>>(h2b, Wvut, bvu, bufA);
    score_act<<<N_TOK / 4, 256, 0, stream>>>(bufA, Ww, bw, scores);
    seg_softmax<<<NSEG, 256, 0, stream>>>(scores);
    pool_partial<<<NSEG * 8, 256, 0, stream>>>(scores, h2b, Zp);
    head_kernel<<<NSEG, 256, 0, stream>>>(Zp, Wc1, bc1, Wc2, bc2, out);
}